// Round 6
// baseline (317.810 us; speedup 1.0000x reference)
//
#include <hip/hip_runtime.h>
#include <stdint.h>

#define D_MODEL 1024
#define N_HEADS 16
#define D_HEAD  64
#define BATCH   4
#define SEQ     4096
#define BS      (BATCH*SEQ)     // 16384
#define QKV_N   (3*D_MODEL)     // 3072
#define HB      (N_HEADS*BATCH) // 64
#define NCHUNK  8
#define CH_S    (SEQ/NCHUNK)    // 512

using f16x8 = __attribute__((ext_vector_type(8))) _Float16;
using f32x4 = __attribute__((ext_vector_type(4))) float;
using i32x4 = __attribute__((ext_vector_type(4))) int;
typedef __attribute__((address_space(3))) ushort AS3U;

__device__ static inline ushort f2h(float f) {
    _Float16 h = (_Float16)f; ushort u; __builtin_memcpy(&u, &h, 2); return u;
}
__device__ static inline void async16(const ushort* g, ushort* l) {
    __builtin_amdgcn_global_load_lds(
        (const __attribute__((address_space(1))) void*)g,
        (__attribute__((address_space(3))) void*)l, 16, 0, 0);
}

// ---------------- K0: fp32 -> fp16 for x and W in one launch ----------------
__global__ __launch_bounds__(256)
void cvt_both(const float* __restrict__ x, const float* __restrict__ W,
              ushort* __restrict__ xh, ushort* __restrict__ Wh, int nx)
{
    int i = (blockIdx.x * 256 + threadIdx.x) * 8;
    const float* src; ushort* dst; int o;
    if (i < nx) { src = x; dst = xh; o = i; }
    else        { src = W; dst = Wh; o = i - nx; }
    float4 a = *(const float4*)(src + o);
    float4 b = *(const float4*)(src + o + 4);
    *(ushort4*)(dst + o)     = make_ushort4(f2h(a.x),f2h(a.y),f2h(a.z),f2h(a.w));
    *(ushort4*)(dst + o + 4) = make_ushort4(f2h(b.x),f2h(b.y),f2h(b.z),f2h(b.w));
}

// ---------------- K1: 128x128-tile TRIPLE-buffered fp16 MFMA GEMM ----------------
// ROUND-6: keep round-5's proven geometry (BM=BN=128, BK=32, 256 thr, 4 waves
// 2Mx2N, acc[4][4], zero spill, zero bank conflicts) and deepen the pipeline
// from depth-1/vmcnt(0) to depth-2/vmcnt(4) (T4 counted wait):
//   - 3 LDS buffers (48 KB total): read buf[t%3], stage buf[(t+2)%3].
//   - step t: vmcnt(4); barrier; ds_read buf[t]; STAGE(t+2); lgkmcnt(0);
//             sched_barrier(0); 16 MFMA.   (ONE barrier/step, at the START)
//   Wait ledger (4 vmem loads per STAGE_AB per wave, FIFO):
//     prologue: stage s0, s1 -> outstanding {s0,s1}.
//     invariant at step-t start: outstanding = {s_t, s_{t+1}}; vmcnt(4)
//     retires s_t (issued during step t-2: ~2-step runway ~600-900 cyc >=
//     HBM latency); during step t issue s_{t+2}. Tail: t=30 VM4 (retires
//     s30), t=31 VM0 (retires s31).
//   Cross-wave safety: each wave's vmcnt only covers its OWN dma loads; the
//     barrier right after the wait makes it block-wide (all waves' stages for
//     buf[t] retired before any wave reads it).
//   Overwrite safety: step t stages buf[(t+2)%3] = the buffer read at step
//     t-1, whose reads were drained by step t-1's lgkmcnt(0) before the
//     barrier that opens step t.
//   MFMA drain overlaps the next step's barrier wait (acc regs not needed
//     until the next MFMA cluster).
// Fragment reads are inline-asm ds_read_b128 (invisible to alias analysis ->
// no compiler-inserted vmcnt(0) between STAGE and reads; rule #18 fence).
// v-type waves compute mfma(B,A) (transposed D) so v stores are ushort4.
#define MF(a,b,c) __builtin_amdgcn_mfma_f32_16x16x32_f16(a,b,c,0,0,0)
#define FENCE asm volatile("" ::: "memory")
#define VM4 asm volatile("s_waitcnt vmcnt(4)" ::: "memory")
#define VM0 asm volatile("s_waitcnt vmcnt(0)" ::: "memory")
#define NOSTAGE do {} while (0)

// asm ds_read_b128: P is an AS3 ushort*, IMM is a byte offset (<65536)
#define DSR(D, P, IMM) do { i32x4 _t; \
    asm volatile("ds_read_b128 %0, %1 offset:%2" : "=v"(_t) : "v"(P), "n"(IMM)); \
    D = __builtin_bit_cast(f16x8, _t); } while (0)

// stage both operands' K-tile KT into buffer NXT (4 vmem loads per wave)
#define STAGE_AB(NXT, KT) do { \
    async16(aS0 + (KT)*32, &lds[(NXT)*4096 + d0]); \
    async16(aS1 + (KT)*32, &lds[(NXT)*4096 + d1]); \
    async16(bS0 + (KT)*32, &lds[12288 + (NXT)*4096 + d0]); \
    async16(bS1 + (KT)*32, &lds[12288 + (NXT)*4096 + d1]); } while (0)

#define STEP(BUF, WAITM, STG) do { \
    WAITM; \
    FENCE; __builtin_amdgcn_s_barrier(); FENCE; \
    f16x8 a0,a1,a2,a3,b0,b1,b2,b3; \
    DSR(a0, lA, (BUF)*8192 + 0);    DSR(a1, lA, (BUF)*8192 + 1024); \
    DSR(a2, lA, (BUF)*8192 + 2048); DSR(a3, lA, (BUF)*8192 + 3072); \
    DSR(b0, lB, (BUF)*8192 + 0);    DSR(b1, lB, (BUF)*8192 + 1024); \
    DSR(b2, lB, (BUF)*8192 + 2048); DSR(b3, lB, (BUF)*8192 + 3072); \
    STG; \
    asm volatile("s_waitcnt lgkmcnt(0)" ::: "memory"); \
    __builtin_amdgcn_sched_barrier(0); \
    __builtin_amdgcn_s_setprio(1); \
    if (!isV) { \
        acc[0][0]=MF(a0,b0,acc[0][0]); acc[0][1]=MF(a0,b1,acc[0][1]); \
        acc[0][2]=MF(a0,b2,acc[0][2]); acc[0][3]=MF(a0,b3,acc[0][3]); \
        acc[1][0]=MF(a1,b0,acc[1][0]); acc[1][1]=MF(a1,b1,acc[1][1]); \
        acc[1][2]=MF(a1,b2,acc[1][2]); acc[1][3]=MF(a1,b3,acc[1][3]); \
        acc[2][0]=MF(a2,b0,acc[2][0]); acc[2][1]=MF(a2,b1,acc[2][1]); \
        acc[2][2]=MF(a2,b2,acc[2][2]); acc[2][3]=MF(a2,b3,acc[2][3]); \
        acc[3][0]=MF(a3,b0,acc[3][0]); acc[3][1]=MF(a3,b1,acc[3][1]); \
        acc[3][2]=MF(a3,b2,acc[3][2]); acc[3][3]=MF(a3,b3,acc[3][3]); \
    } else { \
        acc[0][0]=MF(b0,a0,acc[0][0]); acc[0][1]=MF(b1,a0,acc[0][1]); \
        acc[0][2]=MF(b2,a0,acc[0][2]); acc[0][3]=MF(b3,a0,acc[0][3]); \
        acc[1][0]=MF(b0,a1,acc[1][0]); acc[1][1]=MF(b1,a1,acc[1][1]); \
        acc[1][2]=MF(b2,a1,acc[1][2]); acc[1][3]=MF(b3,a1,acc[1][3]); \
        acc[2][0]=MF(b0,a2,acc[2][0]); acc[2][1]=MF(b1,a2,acc[2][1]); \
        acc[2][2]=MF(b2,a2,acc[2][2]); acc[2][3]=MF(b3,a2,acc[2][3]); \
        acc[3][0]=MF(b0,a3,acc[3][0]); acc[3][1]=MF(b1,a3,acc[3][1]); \
        acc[3][2]=MF(b2,a3,acc[3][2]); acc[3][3]=MF(b3,a3,acc[3][3]); \
    } \
    __builtin_amdgcn_s_setprio(0); \
  } while (0)

__global__ __launch_bounds__(256)
void qkv_gemm_f16(const ushort* __restrict__ Ah, const ushort* __restrict__ Bh,
                  const float* __restrict__ bias,
                  ushort* __restrict__ qh, ushort* __restrict__ kh,
                  ushort* __restrict__ varr)
{
    __shared__ ushort lds[6 * 4096];   // 48 KB: A0,A1,A2 | B0,B1,B2 (8 KB each)
    const int t = threadIdx.x;
    const int lane = t & 63, w = t >> 6;

    // XCD-aware bijective block swizzle (3072 blocks, 3072%8==0)
    const int id0 = blockIdx.y * 24 + blockIdx.x;
    const int ids = (id0 & 7) * 384 + (id0 >> 3);
    const int n0 = (ids % 24) * 128;
    const int m0 = (ids / 24) * 128;

    const int wm = (w >> 1) * 64;      // wave's M offset (2 waves in M)
    const int wn = (w & 1) * 64;       // wave's N offset (2 waves in N)
    const int fr = lane & 15;
    const int hq = lane >> 4;

    // staging: unit u -> row-pair rp=u>>3, phys slot u&7; source pre-swizzled:
    // logical slot8 = phys ^ (rp&7); row = rp*2 + (slot8>>2); col = (slot8&3)*8.
    const int u0 = t, u1 = 256 + t;
    const int rp0 = u0 >> 3, rp1 = u1 >> 3;
    const int sl0 = (u0 & 7) ^ (rp0 & 7), sl1 = (u1 & 7) ^ (rp1 & 7);
    const int r0 = rp0 * 2 + (sl0 >> 2), r1 = rp1 * 2 + (sl1 >> 2);
    const int c0 = (sl0 & 3) * 8,        c1 = (sl1 & 3) * 8;
    const ushort* aS0 = Ah + (size_t)(m0 + r0) * D_MODEL + c0;
    const ushort* aS1 = Ah + (size_t)(m0 + r1) * D_MODEL + c1;
    const ushort* bS0 = Bh + (size_t)(n0 + r0) * D_MODEL + c0;
    const ushort* bS1 = Bh + (size_t)(n0 + r1) * D_MODEL + c1;
    const int d0 = w * 512;            // wave-uniform LDS slice, load 0
    const int d1 = 2048 + w * 512;     // load 1

    // fragment-read offset (lane-constant): row = base + fr, k-slot = hq
    const int rdo  = ((fr >> 1) * 64) + ((((fr & 1) * 4 + hq) ^ ((fr >> 1) & 7)) * 8);
    const AS3U* lA = (const AS3U*)lds + (wm * 32 + rdo);
    const AS3U* lB = (const AS3U*)lds + (12288 + wn * 32 + rdo);

    const int cgb = n0 + wn;                    // 64-aligned output-column base
    const int typ = __builtin_amdgcn_readfirstlane((cgb % 192) / 64); // 0=q,1=k,2=v
    const bool isV = (typ == 2);

    f32x4 acc[4][4] = {};   // q/k: acc[i][j] = D[s i][ci j]; v: transposed

    // ---- prologue: stage kt0->buf0, kt1->buf1 (8 vmem loads outstanding) ----
    STAGE_AB(0, 0);
    STAGE_AB(1, 1);

    // ---- main loop: 32 K-steps, depth-2 counted-vmcnt pipeline ----
    #pragma unroll 1
    for (int it = 0; it < 10; ++it) {
        STEP(0, VM4, STAGE_AB(2, 3*it + 2));
        STEP(1, VM4, STAGE_AB(0, 3*it + 3));
        STEP(2, VM4, STAGE_AB(1, 3*it + 4));
    }
    STEP(0, VM4, NOSTAGE);   // t=30: retires s30; s31 still in flight
    STEP(1, VM0, NOSTAGE);   // t=31: drain s31

    // ---- epilogue: C/D row=(lane>>4)*4+r, col=lane&15 (validated r0-r5) ----
    const int col = lane & 15, rq = (lane >> 4) * 4;
    const int h   = cgb / 192;
    const int b   = m0 >> 12;
    const int sbl = (m0 & 4095) + wm;

    if (typ < 2) {
        ushort* dst = typ ? kh : qh;
        #pragma unroll
        for (int j = 0; j < 4; ++j) {
            const int ci = j*16 + col;
            const float bj = bias[cgb + ci];
            const size_t rowoff = ((size_t)(h*4 + b)*64 + ci) * SEQ;
            #pragma unroll
            for (int i = 0; i < 4; ++i) {
                const int s0 = sbl + i*16 + rq;            // multiple of 4
                float v0 = acc[i][j][0] + bj, v1 = acc[i][j][1] + bj;
                float v2 = acc[i][j][2] + bj, v3 = acc[i][j][3] + bj;
                if (s0 < 32) {
                    // RoPE: angle = ci * 10000^(-mp/16) = ci*exp(-mp*ln1e4/16)
                    int mp = s0 >> 1;
                    float if0 = __expf(-0.5756462732485115f * (float)mp);
                    float if1 = __expf(-0.5756462732485115f * (float)(mp + 1));
                    float a0 = (float)ci * if0, a1 = (float)ci * if1;
                    float cc0 = __cosf(a0), s0n = __sinf(a0);
                    float cc1 = __cosf(a1), s1n = __sinf(a1);
                    float n0_ = v0*cc0 - v1*s0n, n1_ = v1*cc0 + v0*s0n;
                    float n2_ = v2*cc1 - v3*s1n, n3_ = v3*cc1 + v2*s1n;
                    v0 = n0_; v1 = n1_; v2 = n2_; v3 = n3_;
                }
                *(ushort4*)&dst[rowoff + s0] = make_ushort4(
                    f2h(v0), f2h(v1), f2h(v2), f2h(v3));
            }
        }
    } else {
        // swapped-operand acc: acc[i][j][r] is at ci = j*16+rq+r, s = sbl+i*16+col
        const size_t base = (size_t)(h*4 + b) * SEQ;
        #pragma unroll
        for (int j = 0; j < 4; ++j) {
            const float4 b4 = *(const float4*)&bias[cgb + j*16 + rq];
            #pragma unroll
            for (int i = 0; i < 4; ++i) {
                const int s = sbl + i*16 + col;
                *(ushort4*)&varr[(base + s)*64 + j*16 + rq] = make_ushort4(
                    f2h(acc[i][j][0] + b4.x), f2h(acc[i][j][1] + b4.y),
                    f2h(acc[i][j][2] + b4.z), f2h(acc[i][j][3] + b4.w));
            }
        }
    }
}

// ---------------- K2: partial scores (MFMA) per K-chunk ----------------
__global__ __launch_bounds__(256)
void scores_partial(const ushort* __restrict__ qh, const ushort* __restrict__ kh,
                    float* __restrict__ partial)
{
    __shared__ float L[4 * 4096];   // 64 KB: per-wave 64x64 partials
    const int t = threadIdx.x, lane = t & 63, w = t >> 6;
    const int hb = blockIdx.x, chunk = blockIdx.y;
    const ushort* qb = qh + (size_t)hb * 64 * SEQ;
    const ushort* kb = kh + (size_t)hb * 64 * SEQ;
    const int fr = lane & 15, fq = (lane >> 4) * 8;

    f32x4 acc[4][4] = {};
    const int kbase = chunk * CH_S + w * (CH_S / 4);
    for (int kk = 0; kk < CH_S / 4; kk += 32) {
        const int k0 = kbase + kk;
        f16x8 af[4], bf[4];
        #pragma unroll
        for (int i = 0; i < 4; ++i)
            af[i] = *(const f16x8*)&qb[(size_t)(i*16 + fr) * SEQ + k0 + fq];
        #pragma unroll
        for (int j = 0; j < 4; ++j)
            bf[j] = *(const f16x8*)&kb[(size_t)(j*16 + fr) * SEQ + k0 + fq];
        #pragma unroll
        for (int i = 0; i < 4; ++i)
            #pragma unroll
            for (int j = 0; j < 4; ++j)
                acc[i][j] = __builtin_amdgcn_mfma_f32_16x16x32_f16(
                                af[i], bf[j], acc[i][j], 0, 0, 0);
    }

    float* Lw = &L[w * 4096];
    const int col = lane & 15, rq = (lane >> 4) * 4;
    #pragma unroll
    for (int i = 0; i < 4; ++i)
        #pragma unroll
        for (int j = 0; j < 4; ++j)
            #pragma unroll
            for (int r = 0; r < 4; ++r)
                Lw[(i*16 + rq + r)*64 + j*16 + col] = acc[i][j][r];
    __syncthreads();

    float* pb = partial + ((size_t)hb * NCHUNK + chunk) * 4096;
    #pragma unroll
    for (int u = 0; u < 4; ++u) {
        int idx = u*1024 + t*4;
        f32x4 s = *(f32x4*)&L[idx];
        s += *(f32x4*)&L[4096 + idx];
        s += *(f32x4*)&L[8192 + idx];
        s += *(f32x4*)&L[12288 + idx];
        *(f32x4*)&pb[idx] = s;
    }
}

// ---------------- K3: sum chunks, softmax over e; P fp16 [d][e] ----------------
__global__ __launch_bounds__(256)
void softmax_k(const float* __restrict__ partial, ushort* __restrict__ Pt)
{
    __shared__ float L[64 * 65];   // padded: row d at L[d*65]
    const int t = threadIdx.x;
    const int hb = blockIdx.x;
    const float* pb = partial + (size_t)hb * NCHUNK * 4096;

    #pragma unroll
    for (int u = 0; u < 16; ++u) {
        int idx = u*256 + t;              // coalesced global reads
        float s = 0.f;
        #pragma unroll
        for (int c = 0; c < NCHUNK; ++c) s += pb[c*4096 + idx];
        L[(idx >> 6) * 65 + (idx & 63)] = s;
    }
    __syncthreads();

    if (t < 64) {
        float* row = &L[t * 65];          // stride 65: conflict-free across lanes
        float mx = -1e30f;
        for (int e = 0; e < 64; ++e) mx = fmaxf(mx, row[e]);
        float sum = 0.f;
        for (int e = 0; e < 64; ++e) {
            float v = expf(0.125f * (row[e] - mx));
            row[e] = v; sum += v;
        }
        float inv = 1.f / sum;
        ushort* pd = Pt + (size_t)hb * 4096 + t * 64;
        for (int e = 0; e < 64; ++e) pd[e] = f2h(row[e] * inv);
    }
}

// ---------------- K4: out^T[s][d] = sum_e v[s][e] * P[d][e]  (MFMA, K=64) ----------------
__global__ __launch_bounds__(256)
void attn_out_mfma(const ushort* __restrict__ varr, const ushort* __restrict__ Pt,
                   float* __restrict__ out)
{
    const int t = threadIdx.x, lane = t & 63, w = t >> 6;
    const int hb = blockIdx.x;
    const int sb = blockIdx.y * 256 + w * 64;
    const int fr = lane & 15, fq = (lane >> 4) * 8;

    const ushort* Pb = Pt + (size_t)hb * 4096;
    const ushort* vb = varr + (size_t)hb * SEQ * 64;

    f16x8 aV[4][2], bP[4][2];
    #pragma unroll
    for (int i = 0; i < 4; ++i)
        #pragma unroll
        for (int ks = 0; ks < 2; ++ks)
            aV[i][ks] = *(const f16x8*)&vb[(size_t)(sb + i*16 + fr)*64 + ks*32 + fq];
    #pragma unroll
    for (int j = 0; j < 4; ++j)
        #pragma unroll
        for (int ks = 0; ks < 2; ++ks)
            bP[j][ks] = *(const f16x8*)&Pb[(j*16 + fr)*64 + ks*32 + fq];

    f32x4 acc[4][4] = {};   // [s-tile][d-tile]
    #pragma unroll
    for (int ks = 0; ks < 2; ++ks)
        #pragma unroll
        for (int i = 0; i < 4; ++i)
            #pragma unroll
            for (int j = 0; j < 4; ++j)
                acc[i][j] = __builtin_amdgcn_mfma_f32_16x16x32_f16(
                                aV[i][ks], bP[j][ks], acc[i][j], 0, 0, 0);

    const int col = lane & 15, rq = (lane >> 4) * 4;
    const int h = hb >> 2, b = hb & 3;
    #pragma unroll
    for (int i = 0; i < 4; ++i)
        #pragma unroll
        for (int j = 0; j < 4; ++j) {
            const int dg = j*16 + col;
            size_t off = (((size_t)h*64 + dg)*4 + b)*SEQ + sb + i*16 + rq;
            *(float4*)&out[off] = make_float4(acc[i][j][0], acc[i][j][1],
                                              acc[i][j][2], acc[i][j][3]);
        }
}

// ---------------- launcher ----------------
extern "C" void kernel_launch(void* const* d_in, const int* in_sizes, int n_in,
                              void* d_out, int out_size, void* d_ws, size_t ws_size,
                              hipStream_t stream)
{
    const float* x    = (const float*)d_in[0];
    const float* W    = (const float*)d_in[1];
    const float* bias = (const float*)d_in[2];
    float* out = (float*)d_out;

    char* p = (char*)d_ws;
    ushort* qh   = (ushort*)p;  p += (size_t)HB * 64 * SEQ * 2;        // 33.6 MB
    ushort* kh   = (ushort*)p;  p += (size_t)HB * 64 * SEQ * 2;        // 33.6 MB
    ushort* varr = (ushort*)p;  p += (size_t)HB * SEQ * 64 * 2;        // 33.6 MB
    ushort* Pth  = (ushort*)p;  p += (size_t)HB * 4096 * 2;            //  0.5 MB
    float* partial = (float*)p; p += (size_t)HB * NCHUNK * 4096 * 4;   //  8.4 MB
    ushort* xh   = (ushort*)p;  p += (size_t)BS * D_MODEL * 2;         // 33.6 MB
    ushort* Wh   = (ushort*)p;  p += (size_t)QKV_N * D_MODEL * 2;      //  6.3 MB

    const int nx = BS * D_MODEL;       // 16777216
    const int nw = QKV_N * D_MODEL;    // 3145728
    cvt_both<<<(nx + nw)/2048, 256, 0, stream>>>(x, W, xh, Wh, nx);

    qkv_gemm_f16<<<dim3(QKV_N/128, BS/128), 256, 0, stream>>>(
        xh, Wh, bias, qh, kh, varr);

    scores_partial<<<dim3(HB, NCHUNK), 256, 0, stream>>>(qh, kh, partial);
    softmax_k<<<HB, 256, 0, stream>>>(partial, Pth);
    attn_out_mfma<<<dim3(HB, 16), 256, 0, stream>>>(varr, Pth, out);
}

// Round 7
// 298.155 us; speedup vs baseline: 1.0659x; 1.0659x over previous
//
#include <hip/hip_runtime.h>
#include <stdint.h>

#define D_MODEL 1024
#define N_HEADS 16
#define D_HEAD  64
#define BATCH   4
#define SEQ     4096
#define BS      (BATCH*SEQ)     // 16384
#define QKV_N   (3*D_MODEL)     // 3072
#define HB      (N_HEADS*BATCH) // 64
#define NCHUNK  4
#define CH_S    (SEQ/NCHUNK)    // 1024

using f16x8 = __attribute__((ext_vector_type(8))) _Float16;
using f32x4 = __attribute__((ext_vector_type(4))) float;
using i32x4 = __attribute__((ext_vector_type(4))) int;
typedef __attribute__((address_space(3))) ushort AS3U;

__device__ static inline ushort f2h(float f) {
    _Float16 h = (_Float16)f; ushort u; __builtin_memcpy(&u, &h, 2); return u;
}
__device__ static inline void async16(const ushort* g, ushort* l) {
    __builtin_amdgcn_global_load_lds(
        (const __attribute__((address_space(1))) void*)g,
        (__attribute__((address_space(3))) void*)l, 16, 0, 0);
}

// ---------------- K0: fp32 -> fp16 for x and W in one launch ----------------
__global__ __launch_bounds__(256)
void cvt_both(const float* __restrict__ x, const float* __restrict__ W,
              ushort* __restrict__ xh, ushort* __restrict__ Wh, int nx)
{
    int i = (blockIdx.x * 256 + threadIdx.x) * 8;
    const float* src; ushort* dst; int o;
    if (i < nx) { src = x; dst = xh; o = i; }
    else        { src = W; dst = Wh; o = i - nx; }
    float4 a = *(const float4*)(src + o);
    float4 b = *(const float4*)(src + o + 4);
    *(ushort4*)(dst + o)     = make_ushort4(f2h(a.x),f2h(a.y),f2h(a.z),f2h(a.w));
    *(ushort4*)(dst + o + 4) = make_ushort4(f2h(b.x),f2h(b.y),f2h(b.z),f2h(b.w));
}

// ---------------- K1: 128x128-tile double-buffered fp16 MFMA GEMM ----------------
// ROUND-7: EXACT revert to the round-5 kernel (measured 150 µs, VGPR 128,
// WRITE=payload, 0 bank conflicts). Round-6's depth-2/3-buffer variant
// regressed (VGPR 160 + LDS 48KB -> 3 blocks/CU, FETCH 2x): reverted.
// 687 TF ~= the 2-phase 128^2 structure's measured ceiling (m230/m233);
// structure kept as-is.
#define MF(a,b,c) __builtin_amdgcn_mfma_f32_16x16x32_f16(a,b,c,0,0,0)
#define FENCE asm volatile("" ::: "memory")
#define VM0 asm volatile("s_waitcnt vmcnt(0)" ::: "memory")

// asm ds_read_b128: P is an AS3 ushort*, IMM is a byte offset (<65536)
#define DSR(D, P, IMM) do { i32x4 _t; \
    asm volatile("ds_read_b128 %0, %1 offset:%2" : "=v"(_t) : "v"(P), "n"(IMM)); \
    D = __builtin_bit_cast(f16x8, _t); } while (0)

// stage both operands' next chunk (4 x global_load_lds_dwordx4 per thread)
#define STAGE_AB(NXT, KT) do { \
    async16(aS0 + (KT)*32, &lds[(NXT)*4096 + d0]); \
    async16(aS1 + (KT)*32, &lds[(NXT)*4096 + d1]); \
    async16(bS0 + (KT)*32, &lds[8192 + (NXT)*4096 + d0]); \
    async16(bS1 + (KT)*32, &lds[8192 + (NXT)*4096 + d1]); } while (0)

#define STEP(CUR, STG) do { \
    STG; \
    const AS3U* pa = lA + (CUR)*4096; \
    const AS3U* pb = lB + (CUR)*4096; \
    f16x8 a0,a1,a2,a3,b0,b1,b2,b3; \
    DSR(a0, pa, 0); DSR(a1, pa, 1024); DSR(a2, pa, 2048); DSR(a3, pa, 3072); \
    DSR(b0, pb, 0); DSR(b1, pb, 1024); DSR(b2, pb, 2048); DSR(b3, pb, 3072); \
    asm volatile("s_waitcnt lgkmcnt(0)" ::: "memory"); \
    __builtin_amdgcn_sched_barrier(0); \
    __builtin_amdgcn_s_setprio(1); \
    if (!isV) { \
        acc[0][0]=MF(a0,b0,acc[0][0]); acc[0][1]=MF(a0,b1,acc[0][1]); \
        acc[0][2]=MF(a0,b2,acc[0][2]); acc[0][3]=MF(a0,b3,acc[0][3]); \
        acc[1][0]=MF(a1,b0,acc[1][0]); acc[1][1]=MF(a1,b1,acc[1][1]); \
        acc[1][2]=MF(a1,b2,acc[1][2]); acc[1][3]=MF(a1,b3,acc[1][3]); \
        acc[2][0]=MF(a2,b0,acc[2][0]); acc[2][1]=MF(a2,b1,acc[2][1]); \
        acc[2][2]=MF(a2,b2,acc[2][2]); acc[2][3]=MF(a2,b3,acc[2][3]); \
        acc[3][0]=MF(a3,b0,acc[3][0]); acc[3][1]=MF(a3,b1,acc[3][1]); \
        acc[3][2]=MF(a3,b2,acc[3][2]); acc[3][3]=MF(a3,b3,acc[3][3]); \
    } else { \
        acc[0][0]=MF(b0,a0,acc[0][0]); acc[0][1]=MF(b1,a0,acc[0][1]); \
        acc[0][2]=MF(b2,a0,acc[0][2]); acc[0][3]=MF(b3,a0,acc[0][3]); \
        acc[1][0]=MF(b0,a1,acc[1][0]); acc[1][1]=MF(b1,a1,acc[1][1]); \
        acc[1][2]=MF(b2,a1,acc[1][2]); acc[1][3]=MF(b3,a1,acc[1][3]); \
        acc[2][0]=MF(b0,a2,acc[2][0]); acc[2][1]=MF(b1,a2,acc[2][1]); \
        acc[2][2]=MF(b2,a2,acc[2][2]); acc[2][3]=MF(b3,a2,acc[2][3]); \
        acc[3][0]=MF(b0,a3,acc[3][0]); acc[3][1]=MF(b1,a3,acc[3][1]); \
        acc[3][2]=MF(b2,a3,acc[3][2]); acc[3][3]=MF(b3,a3,acc[3][3]); \
    } \
    __builtin_amdgcn_s_setprio(0); \
    VM0; \
    FENCE; __builtin_amdgcn_s_barrier(); FENCE; \
  } while (0)

__global__ __launch_bounds__(256)
void qkv_gemm_f16(const ushort* __restrict__ Ah, const ushort* __restrict__ Bh,
                  const float* __restrict__ bias,
                  ushort* __restrict__ qh, ushort* __restrict__ kh,
                  ushort* __restrict__ varr)
{
    __shared__ ushort lds[4 * 4096];   // 32 KB: A0,A1,B0,B1 chunks of 8 KB
    const int t = threadIdx.x;
    const int lane = t & 63, w = t >> 6;

    // XCD-aware bijective block swizzle (3072 blocks, 3072%8==0)
    const int id0 = blockIdx.y * 24 + blockIdx.x;
    const int ids = (id0 & 7) * 384 + (id0 >> 3);
    const int n0 = (ids % 24) * 128;
    const int m0 = (ids / 24) * 128;

    const int wm = (w >> 1) * 64;      // wave's M offset (2 waves in M)
    const int wn = (w & 1) * 64;       // wave's N offset (2 waves in N)
    const int fr = lane & 15;
    const int hq = lane >> 4;

    // staging: unit u -> row-pair rp=u>>3, phys slot u&7; source pre-swizzled:
    // logical slot8 = phys ^ (rp&7); row = rp*2 + (slot8>>2); col = (slot8&3)*8.
    const int u0 = t, u1 = 256 + t;
    const int rp0 = u0 >> 3, rp1 = u1 >> 3;
    const int sl0 = (u0 & 7) ^ (rp0 & 7), sl1 = (u1 & 7) ^ (rp1 & 7);
    const int r0 = rp0 * 2 + (sl0 >> 2), r1 = rp1 * 2 + (sl1 >> 2);
    const int c0 = (sl0 & 3) * 8,        c1 = (sl1 & 3) * 8;
    const ushort* aS0 = Ah + (size_t)(m0 + r0) * D_MODEL + c0;
    const ushort* aS1 = Ah + (size_t)(m0 + r1) * D_MODEL + c1;
    const ushort* bS0 = Bh + (size_t)(n0 + r0) * D_MODEL + c0;
    const ushort* bS1 = Bh + (size_t)(n0 + r1) * D_MODEL + c1;
    const int d0 = w * 512;            // wave-uniform LDS slice, load 0
    const int d1 = 2048 + w * 512;     // load 1

    // fragment-read offset (lane-constant): row = base + fr, k-slot = hq
    const int rdo  = ((fr >> 1) * 64) + ((((fr & 1) * 4 + hq) ^ ((fr >> 1) & 7)) * 8);
    const AS3U* lA = (const AS3U*)lds + (wm * 32 + rdo);
    const AS3U* lB = (const AS3U*)lds + (8192 + wn * 32 + rdo);

    const int cgb = n0 + wn;                    // 64-aligned output-column base
    const int typ = __builtin_amdgcn_readfirstlane((cgb % 192) / 64); // 0=q,1=k,2=v
    const bool isV = (typ == 2);

    f32x4 acc[4][4] = {};   // q/k: acc[i][j] = D[s i][ci j]; v: transposed

    // ---- prologue ----
    STAGE_AB(0, 0);
    VM0;
    __builtin_amdgcn_s_barrier();
    FENCE;

    // ---- main loop: 32 K-steps, double-buffered, 1 barrier/step ----
    #pragma unroll 1
    for (int it = 0; it < 15; ++it) {
        STEP(0, STAGE_AB(1, 2*it + 1));
        STEP(1, STAGE_AB(0, 2*it + 2));
    }
    STEP(0, STAGE_AB(1, 31));
    STEP(1, );

    // ---- epilogue: C/D row=(lane>>4)*4+r, col=lane&15 (validated r0-r6) ----
    const int col = lane & 15, rq = (lane >> 4) * 4;
    const int h   = cgb / 192;
    const int b   = m0 >> 12;
    const int sbl = (m0 & 4095) + wm;

    if (typ < 2) {
        ushort* dst = typ ? kh : qh;
        #pragma unroll
        for (int j = 0; j < 4; ++j) {
            const int ci = j*16 + col;
            const float bj = bias[cgb + ci];
            const size_t rowoff = ((size_t)(h*4 + b)*64 + ci) * SEQ;
            #pragma unroll
            for (int i = 0; i < 4; ++i) {
                const int s0 = sbl + i*16 + rq;            // multiple of 4
                float v0 = acc[i][j][0] + bj, v1 = acc[i][j][1] + bj;
                float v2 = acc[i][j][2] + bj, v3 = acc[i][j][3] + bj;
                if (s0 < 32) {
                    // RoPE: angle = ci * 10000^(-mp/16) = ci*exp(-mp*ln1e4/16)
                    int mp = s0 >> 1;
                    float if0 = __expf(-0.5756462732485115f * (float)mp);
                    float if1 = __expf(-0.5756462732485115f * (float)(mp + 1));
                    float a0 = (float)ci * if0, a1 = (float)ci * if1;
                    float cc0 = __cosf(a0), s0n = __sinf(a0);
                    float cc1 = __cosf(a1), s1n = __sinf(a1);
                    float n0_ = v0*cc0 - v1*s0n, n1_ = v1*cc0 + v0*s0n;
                    float n2_ = v2*cc1 - v3*s1n, n3_ = v3*cc1 + v2*s1n;
                    v0 = n0_; v1 = n1_; v2 = n2_; v3 = n3_;
                }
                *(ushort4*)&dst[rowoff + s0] = make_ushort4(
                    f2h(v0), f2h(v1), f2h(v2), f2h(v3));
            }
        }
    } else {
        // swapped-operand acc: acc[i][j][r] is at ci = j*16+rq+r, s = sbl+i*16+col
        const size_t base = (size_t)(h*4 + b) * SEQ;
        #pragma unroll
        for (int j = 0; j < 4; ++j) {
            const float4 b4 = *(const float4*)&bias[cgb + j*16 + rq];
            #pragma unroll
            for (int i = 0; i < 4; ++i) {
                const int s = sbl + i*16 + col;
                *(ushort4*)&varr[(base + s)*64 + j*16 + rq] = make_ushort4(
                    f2h(acc[i][j][0] + b4.x), f2h(acc[i][j][1] + b4.y),
                    f2h(acc[i][j][2] + b4.z), f2h(acc[i][j][3] + b4.w));
            }
        }
    }
}

// ---------------- K2: partial scores (MFMA) per K-chunk ----------------
// ROUND-7: NCHUNK 8->4 (256 blocks = exactly 1/CU): halves partial traffic
// and the per-block LDS-reduce overhead per K-element.
__global__ __launch_bounds__(256)
void scores_partial(const ushort* __restrict__ qh, const ushort* __restrict__ kh,
                    float* __restrict__ partial)
{
    __shared__ float L[4 * 4096];   // 64 KB: per-wave 64x64 partials
    const int t = threadIdx.x, lane = t & 63, w = t >> 6;
    const int hb = blockIdx.x, chunk = blockIdx.y;
    const ushort* qb = qh + (size_t)hb * 64 * SEQ;
    const ushort* kb = kh + (size_t)hb * 64 * SEQ;
    const int fr = lane & 15, fq = (lane >> 4) * 8;

    f32x4 acc[4][4] = {};
    const int kbase = chunk * CH_S + w * (CH_S / 4);
    for (int kk = 0; kk < CH_S / 4; kk += 32) {
        const int k0 = kbase + kk;
        f16x8 af[4], bf[4];
        #pragma unroll
        for (int i = 0; i < 4; ++i)
            af[i] = *(const f16x8*)&qb[(size_t)(i*16 + fr) * SEQ + k0 + fq];
        #pragma unroll
        for (int j = 0; j < 4; ++j)
            bf[j] = *(const f16x8*)&kb[(size_t)(j*16 + fr) * SEQ + k0 + fq];
        #pragma unroll
        for (int i = 0; i < 4; ++i)
            #pragma unroll
            for (int j = 0; j < 4; ++j)
                acc[i][j] = __builtin_amdgcn_mfma_f32_16x16x32_f16(
                                af[i], bf[j], acc[i][j], 0, 0, 0);
    }

    float* Lw = &L[w * 4096];
    const int col = lane & 15, rq = (lane >> 4) * 4;
    #pragma unroll
    for (int i = 0; i < 4; ++i)
        #pragma unroll
        for (int j = 0; j < 4; ++j)
            #pragma unroll
            for (int r = 0; r < 4; ++r)
                Lw[(i*16 + rq + r)*64 + j*16 + col] = acc[i][j][r];
    __syncthreads();

    float* pb = partial + ((size_t)hb * NCHUNK + chunk) * 4096;
    #pragma unroll
    for (int u = 0; u < 4; ++u) {
        int idx = u*1024 + t*4;
        f32x4 s = *(f32x4*)&L[idx];
        s += *(f32x4*)&L[4096 + idx];
        s += *(f32x4*)&L[8192 + idx];
        s += *(f32x4*)&L[12288 + idx];
        *(f32x4*)&pb[idx] = s;
    }
}

// ---------------- K4: fused softmax + out^T[s][d] = sum_e v[s][e] * P[d][e] ----------------
// ROUND-7: K3 deleted; each block recomputes P[hb] from `partial` in its
// prologue (4-lane-per-row parallel softmax, all 256 threads active), stages
// P in padded LDS ([64][72] ushort: 144B row stride -> 2-way conflict = free),
// then runs the MFMA exactly as before with bP read from LDS.
__global__ __launch_bounds__(256)
void attn_out_mfma(const ushort* __restrict__ varr, const float* __restrict__ partial,
                   float* __restrict__ out)
{
    __shared__ ushort P_lds[64 * 72];   // 9 KB, padded
    const int t = threadIdx.x, lane = t & 63, w = t >> 6;
    const int hb = blockIdx.x;
    const int sb = blockIdx.y * 256 + w * 64;
    const int fr = lane & 15, fq = (lane >> 4) * 8;

    // ---- fused chunk-sum + softmax over e ----
    {
        const float* pb = partial + (size_t)hb * NCHUNK * 4096;
        const int row = t >> 2, l4 = t & 3;   // 64 rows x 4 lanes; e = l4*16+i
        const int eb = row*64 + l4*16;
        float s[16];
        #pragma unroll
        for (int i = 0; i < 16; ++i) {
            float a = 0.f;
            #pragma unroll
            for (int c = 0; c < NCHUNK; ++c) a += pb[c*4096 + eb + i];
            s[i] = a * 0.125f;
        }
        float mx = s[0];
        #pragma unroll
        for (int i = 1; i < 16; ++i) mx = fmaxf(mx, s[i]);
        mx = fmaxf(mx, __shfl_xor(mx, 1));
        mx = fmaxf(mx, __shfl_xor(mx, 2));
        float sum = 0.f;
        #pragma unroll
        for (int i = 0; i < 16; ++i) { s[i] = __expf(s[i] - mx); sum += s[i]; }
        sum += __shfl_xor(sum, 1);
        sum += __shfl_xor(sum, 2);
        const float inv = 1.f / sum;
        #pragma unroll
        for (int i = 0; i < 16; ++i)
            P_lds[row*72 + l4*16 + i] = f2h(s[i] * inv);
    }
    __syncthreads();

    const ushort* vb = varr + (size_t)hb * SEQ * 64;

    f16x8 aV[4][2], bP[4][2];
    #pragma unroll
    for (int i = 0; i < 4; ++i)
        #pragma unroll
        for (int ks = 0; ks < 2; ++ks)
            aV[i][ks] = *(const f16x8*)&vb[(size_t)(sb + i*16 + fr)*64 + ks*32 + fq];
    #pragma unroll
    for (int j = 0; j < 4; ++j)
        #pragma unroll
        for (int ks = 0; ks < 2; ++ks)
            bP[j][ks] = *(const f16x8*)&P_lds[(j*16 + fr)*72 + ks*32 + fq];

    f32x4 acc[4][4] = {};   // [s-tile][d-tile]
    #pragma unroll
    for (int ks = 0; ks < 2; ++ks)
        #pragma unroll
        for (int i = 0; i < 4; ++i)
            #pragma unroll
            for (int j = 0; j < 4; ++j)
                acc[i][j] = __builtin_amdgcn_mfma_f32_16x16x32_f16(
                                aV[i][ks], bP[j][ks], acc[i][j], 0, 0, 0);

    const int col = lane & 15, rq = (lane >> 4) * 4;
    const int h = hb >> 2, b = hb & 3;
    #pragma unroll
    for (int i = 0; i < 4; ++i)
        #pragma unroll
        for (int j = 0; j < 4; ++j) {
            const int dg = j*16 + col;
            size_t off = (((size_t)h*64 + dg)*4 + b)*SEQ + sb + i*16 + rq;
            *(float4*)&out[off] = make_float4(acc[i][j][0], acc[i][j][1],
                                              acc[i][j][2], acc[i][j][3]);
        }
}

// ---------------- launcher ----------------
extern "C" void kernel_launch(void* const* d_in, const int* in_sizes, int n_in,
                              void* d_out, int out_size, void* d_ws, size_t ws_size,
                              hipStream_t stream)
{
    const float* x    = (const float*)d_in[0];
    const float* W    = (const float*)d_in[1];
    const float* bias = (const float*)d_in[2];
    float* out = (float*)d_out;

    char* p = (char*)d_ws;
    ushort* qh   = (ushort*)p;  p += (size_t)HB * 64 * SEQ * 2;        // 33.6 MB
    ushort* kh   = (ushort*)p;  p += (size_t)HB * 64 * SEQ * 2;        // 33.6 MB
    ushort* varr = (ushort*)p;  p += (size_t)HB * SEQ * 64 * 2;        // 33.6 MB
    float* partial = (float*)p; p += (size_t)HB * NCHUNK * 4096 * 4;   //  4.2 MB
    ushort* xh   = (ushort*)p;  p += (size_t)BS * D_MODEL * 2;         // 33.6 MB
    ushort* Wh   = (ushort*)p;  p += (size_t)QKV_N * D_MODEL * 2;      //  6.3 MB

    const int nx = BS * D_MODEL;       // 16777216
    const int nw = QKV_N * D_MODEL;    // 3145728
    cvt_both<<<(nx + nw)/2048, 256, 0, stream>>>(x, W, xh, Wh, nx);

    qkv_gemm_f16<<<dim3(QKV_N/128, BS/128), 256, 0, stream>>>(
        xh, Wh, bias, qh, kh, varr);

    scores_partial<<<dim3(HB, NCHUNK), 256, 0, stream>>>(qh, kh, partial);
    attn_out_mfma<<<dim3(HB, 16), 256, 0, stream>>>(varr, partial, out);
}